// Round 4
// baseline (170.904 us; speedup 1.0000x reference)
//
#include <hip/hip_runtime.h>

#define TH 16              // output rows per block
#define NIT (TH + 4)       // pipeline iterations (4 warm-up/halo rows)

__global__ __launch_bounds__(512, 4)
void bilateral_fused(const float* __restrict__ bright,
                     const float* __restrict__ dark,
                     const float* __restrict__ depths,
                     const float* __restrict__ p_dv,
                     const float* __restrict__ p_sv,
                     const float* __restrict__ p_de,
                     const float* __restrict__ p_deps,
                     const float* __restrict__ p_ce,
                     float* __restrict__ out,
                     int H, int W)
{
    const float LOG2E = 1.44269504088896340736f;
    const float kd  = -LOG2E / (2.0f * p_dv[0]);   // ~ -1803: weight underflows
    const float ks  = -LOG2E / (2.0f * p_sv[0]);   //   to exact 0 for rel>~0.29
    const float de  = p_de[0];
    const float dke = p_deps[0];
    const float ce  = p_ce[0];
    const float ks1 = ks;
    const float ks4 = 4.0f * ks;
    const float NEG = -1e30f;   // exp2(-1e30 + finite) == 0.0f exactly

    const int t  = threadIdx.x;          // 0..511
    const int c  = 2 * t;                // this thread's cols c, c+1 (c even)
    const int y0 = blockIdx.y * TH;

    const size_t plane = (size_t)H * W;
    const float* bB = bright + (size_t)blockIdx.z * plane;
    const float* dB = dark   + (size_t)blockIdx.z * plane;
    const float* zB = depths + (size_t)blockIdx.z * plane;
    float*     outB = out    + (size_t)blockIdx.z * plane;

    // clamped side-window columns (8B aligned); garbage taps are weight-masked
    const int colL = max(c - 2, 0);
    const int colR = min(c + 2, W - 2);

    // per-thread spatial-exponent constants with column zero-pad folded in:
    // OOB tap -> exponent -1e30 -> weight exactly 0 (matches zero-pad ref)
    const float kA0 = (c - 2 >= 0) ? ks4 : NEG;   // px0 tap col c-2
    const float kA1 = (c - 1 >= 0) ? ks1 : NEG;   // px0 tap col c-1
    const float kA3 = ks1;                        // px0 tap col c+1 (always ok)
    const float kA4 = (c + 2 <  W) ? ks4 : NEG;   // px0 tap col c+2
    const float kB0 = (c - 1 >= 0) ? ks4 : NEG;   // px1 tap col c-1
    const float kB1 = ks1;                        // px1 tap col c   (always ok)
    const float kB3 = (c + 2 <  W) ? ks1 : NEG;   // px1 tap col c+2
    const float kB4 = (c + 3 <  W) ? ks4 : NEG;   // px1 tap col c+3

    auto wexp = [&](float zp, float invz, float kspat) {
        const float u = fmaf(zp, invz, -1.0f);
        return exp2f(fmaf(u * kd, u, kspat));
    };

    // 5-deep register pipeline of horizontally-blurred rows (+ center depths)
    float pb0[5], pb1[5], pd0[5], pd1[5], pz0[5], pz1[5];

#pragma unroll
    for (int i = 0; i < NIT; ++i) {
        const int s  = i % 5;            // static after full unroll
        const int gy = y0 + i - 2;

        if ((unsigned)gy < (unsigned)H) {    // block-uniform branch
            const size_t ro = (size_t)gy * W;
            const float2 bL = *(const float2*)(bB + ro + colL);
            const float2 bC = *(const float2*)(bB + ro + c);
            const float2 bR = *(const float2*)(bB + ro + colR);
            const float2 dL = *(const float2*)(dB + ro + colL);
            const float2 dC = *(const float2*)(dB + ro + c);
            const float2 dR = *(const float2*)(dB + ro + colR);
            const float2 zL = *(const float2*)(zB + ro + colL);
            const float2 zC = *(const float2*)(zB + ro + c);
            const float2 zR = *(const float2*)(zB + ro + colR);

            // px0 (col c): taps c-2,c-1,[c],c+1,c+2
            const float iA = __builtin_amdgcn_rcpf(zC.x);
            const float w0 = wexp(zL.x, iA, kA0);
            const float w1 = wexp(zL.y, iA, kA1);
            const float w3 = wexp(zC.y, iA, kA3);
            const float w4 = wexp(zR.x, iA, kA4);
            const float wr = __builtin_amdgcn_rcpf(1.0f + w0 + w1 + w3 + w4);
            pb0[s] = fmaf(w0, bL.x, fmaf(w1, bL.y, fmaf(w3, bC.y, fmaf(w4, bR.x, bC.x)))) * wr;
            pd0[s] = fmaf(w0, dL.x, fmaf(w1, dL.y, fmaf(w3, dC.y, fmaf(w4, dR.x, dC.x)))) * wr;
            pz0[s] = zC.x;

            // px1 (col c+1): taps c-1,c,[c+1],c+2,c+3
            const float iB = __builtin_amdgcn_rcpf(zC.y);
            const float u0 = wexp(zL.y, iB, kB0);
            const float u1 = wexp(zC.x, iB, kB1);
            const float u3 = wexp(zR.x, iB, kB3);
            const float u4 = wexp(zR.y, iB, kB4);
            const float ur = __builtin_amdgcn_rcpf(1.0f + u0 + u1 + u3 + u4);
            pb1[s] = fmaf(u0, bL.y, fmaf(u1, bC.x, fmaf(u3, bR.x, fmaf(u4, bR.y, bC.y)))) * ur;
            pd1[s] = fmaf(u0, dL.y, fmaf(u1, dC.x, fmaf(u3, dR.x, fmaf(u4, dR.y, dC.y)))) * ur;
            pz1[s] = zC.y;
        } else {
            // zero-pad row: z=0 -> vertical tap weight underflows to exact 0
            pb0[s] = pb1[s] = pd0[s] = pd1[s] = 0.0f;
            pz0[s] = pz1[s] = 0.0f;
        }

        if (i >= 4) {
            const int orow = y0 + i - 4;           // output row (always valid)
            const int sm2 = (i - 4) % 5, sm1 = (i - 3) % 5, sc = (i - 2) % 5;
            const int sp1 = (i - 1) % 5, sp2 = i % 5;

            // vertical blur px0
            const float izA = __builtin_amdgcn_rcpf(pz0[sc]);
            const float v0 = wexp(pz0[sm2], izA, ks4);
            const float v1 = wexp(pz0[sm1], izA, ks1);
            const float v3 = wexp(pz0[sp1], izA, ks1);
            const float v4 = wexp(pz0[sp2], izA, ks4);
            const float vr = __builtin_amdgcn_rcpf(1.0f + v0 + v1 + v3 + v4);
            const float bmA = fmaf(v0, pb0[sm2], fmaf(v1, pb0[sm1], fmaf(v3, pb0[sp1], fmaf(v4, pb0[sp2], pb0[sc])))) * vr;
            const float dmA = fmaf(v0, pd0[sm2], fmaf(v1, pd0[sm1], fmaf(v3, pd0[sp1], fmaf(v4, pd0[sp2], pd0[sc])))) * vr;

            // vertical blur px1
            const float izB = __builtin_amdgcn_rcpf(pz1[sc]);
            const float x0 = wexp(pz1[sm2], izB, ks4);
            const float x1 = wexp(pz1[sm1], izB, ks1);
            const float x3 = wexp(pz1[sp1], izB, ks1);
            const float x4 = wexp(pz1[sp2], izB, ks4);
            const float xr = __builtin_amdgcn_rcpf(1.0f + x0 + x1 + x3 + x4);
            const float bmB = fmaf(x0, pb1[sm2], fmaf(x1, pb1[sm1], fmaf(x3, pb1[sp1], fmaf(x4, pb1[sp2], pb1[sc])))) * xr;
            const float dmB = fmaf(x0, pd1[sm2], fmaf(x1, pd1[sm1], fmaf(x3, pd1[sp1], fmaf(x4, pd1[sp2], pd1[sc])))) * xr;

            // contrast blend (raw center re-read: L1-hot, loaded 2 iters ago)
            const size_t oo = (size_t)orow * W + c;
            const float2 bc = *(const float2*)(bB + oo);
            const float2 dc = *(const float2*)(dB + oo);

            const float devbA = exp2f(de * __log2f(fmaxf(fabsf(bc.x - bmA), 1e-8f))) * ce;
            const float devdA = fmaxf(exp2f(de * __log2f(fmaxf(fabsf(dc.x - dmA), 1e-8f))), dke);
            const float wA = __builtin_amdgcn_rcpf(devbA + devdA);
            const float resA = fmaf(devdA, bc.x, devbA * dc.x) * wA;

            const float devbB = exp2f(de * __log2f(fmaxf(fabsf(bc.y - bmB), 1e-8f))) * ce;
            const float devdB = fmaxf(exp2f(de * __log2f(fmaxf(fabsf(dc.y - dmB), 1e-8f))), dke);
            const float wB = __builtin_amdgcn_rcpf(devbB + devdB);
            const float resB = fmaf(devdB, bc.y, devbB * dc.y) * wB;

            *(float2*)(outB + oo) = make_float2(resA, resB);
        }
    }
}

extern "C" void kernel_launch(void* const* d_in, const int* in_sizes, int n_in,
                              void* d_out, int out_size, void* d_ws, size_t ws_size,
                              hipStream_t stream)
{
    const float* bright = (const float*)d_in[0];
    const float* dark   = (const float*)d_in[1];
    const float* depths = (const float*)d_in[2];
    const float* p_dv   = (const float*)d_in[3];
    const float* p_sv   = (const float*)d_in[4];
    const float* p_de   = (const float*)d_in[5];
    const float* p_deps = (const float*)d_in[6];
    const float* p_ce   = (const float*)d_in[7];
    float* out = (float*)d_out;

    const int H = 1024, W = 1024;
    const int B = in_sizes[0] / (H * W);

    dim3 grid(1, H / TH, B);
    dim3 block(512);
    bilateral_fused<<<grid, block, 0, stream>>>(bright, dark, depths,
                                                p_dv, p_sv, p_de, p_deps, p_ce,
                                                out, H, W);
}